// Round 1
// baseline (1419.120 us; speedup 1.0000x reference)
//
#include <hip/hip_runtime.h>
#include <math.h>

#define BS      4096
#define DM      256
#define DINNER  2048
#define DSTATE  16

typedef float f32x4 __attribute__((ext_vector_type(4)));

__device__ __forceinline__ float silu_f(float x) {
    return x / (1.f + __expf(-x));
}

__device__ __forceinline__ float softplus_f(float x) {
    if (x > 20.f) return x;
    if (x < -20.f) return __expf(x);
    return __logf(1.f + __expf(x));
}

// wave-uniform value -> SGPR
__device__ __forceinline__ float rfl(float x) {
    return __int_as_float(__builtin_amdgcn_readfirstlane(__float_as_int(x)));
}

__global__ void a_precompute_kernel(const float* __restrict__ A_log,
                                    float* __restrict__ A) {
    int i = blockIdx.x * 256 + threadIdx.x;   // 32768 total
    A[i] = -__expf(A_log[i]);
}

__global__ __launch_bounds__(256, 4)
void flow_main_kernel(const float* __restrict__ bbox,
                      const float* __restrict__ h_in,
                      const float* __restrict__ flow_embed,
                      const float* __restrict__ W_in,
                      const float* __restrict__ b_in,
                      const float* __restrict__ W_dt,
                      const float* __restrict__ b_dt,
                      const float* __restrict__ W_flow,
                      const float* __restrict__ Aptr,  // -exp(A_log) if a_ready, else A_log
                      int a_ready,
                      const float* __restrict__ Dvec,
                      const float* __restrict__ W_out,
                      const float* __restrict__ b_out,
                      float* __restrict__ out,
                      float* __restrict__ h_out)
{
    __shared__ __align__(16) float fe_s[DM];
    __shared__ float pp_s[48][4];
    __shared__ __align__(16) float proj_s[48];
    __shared__ float red_s[4][4];

    const int b = blockIdx.x;
    const int t = threadIdx.x;

    // ---- phase 0: flow_embed row to LDS, proj_f = fe @ W_flow.T (48 outputs)
    fe_s[t] = flow_embed[b * DM + t];
    __syncthreads();

    if (t < 192) {
        const int k = t >> 2, p = t & 3;
        const float4* wf  = (const float4*)(W_flow + k * DM);
        const float4* fe4 = (const float4*)fe_s;
        float s = 0.f;
        #pragma unroll
        for (int i = 0; i < 16; ++i) {
            float4 w = wf[p * 16 + i];
            float4 f = fe4[p * 16 + i];
            s += w.x * f.x + w.y * f.y + w.z * f.z + w.w * f.w;
        }
        pp_s[k][p] = s;
    }
    __syncthreads();
    if (t < 48)
        proj_s[t] = pp_s[t][0] + pp_s[t][1] + pp_s[t][2] + pp_s[t][3];
    __syncthreads();

    // ---- wave-uniform scalars into SGPRs: dt_low (16), B (16), C (16)
    float dl[16], Bn[16], Cn[16];
    #pragma unroll
    for (int n = 0; n < 16; ++n) {
        dl[n] = rfl(proj_s[n]);
        Bn[n] = rfl(proj_s[16 + n]);
        Cn[n] = rfl(proj_s[32 + n]);
    }

    const float4 bb = ((const float4*)bbox)[b];
    const float4* __restrict__ hin4  = (const float4*)(h_in + (size_t)b * 32768);
    float4* __restrict__       hout4 = (float4*)(h_out + (size_t)b * 32768);
    const float4* __restrict__ A4    = (const float4*)Aptr;

    float acc0 = 0.f, acc1 = 0.f, acc2 = 0.f, acc3 = 0.f;

    // ---- main loop: thread t owns full state rows d = i*256 + t.
    // Each iteration: 4 h-float4 + 4 A-float4 + weight loads, all independent;
    // no LDS, no shuffles, no divergence in the loop body.
    #pragma unroll
    for (int i = 0; i < 8; ++i) {
        const int d = i * 256 + t;
        const int q = d * 4;                  // float4 index of row start

        // streaming loads first (HBM / L3)
        float4 h0 = hin4[q + 0], h1 = hin4[q + 1], h2 = hin4[q + 2], h3 = hin4[q + 3];
        float4 a0 = A4[q + 0],   a1 = A4[q + 1],   a2 = A4[q + 2],   a3 = A4[q + 3];

        // per-d weights (L2-resident), coalesced across lanes
        float4 wi = ((const float4*)W_in)[d];
        float4 wr = ((const float4*)W_in)[DINNER + d];
        const float4* wd = (const float4*)(W_dt + d * 16);
        float4 w0 = wd[0], w1 = wd[1], w2 = wd[2], w3 = wd[3];
        const float bi_e = b_in[d];
        const float bi_r = b_in[DINNER + d];
        const float bdt  = b_dt[d];
        const float dd   = Dvec[d];
        const float wo0  = W_out[d];
        const float wo1  = W_out[DINNER + d];
        const float wo2  = W_out[2 * DINNER + d];
        const float wo3  = W_out[3 * DINNER + d];

        // per-d scalars
        float e = fmaf(bb.x, wi.x, fmaf(bb.y, wi.y, fmaf(bb.z, wi.z, bb.w * wi.w))) + bi_e;
        e = silu_f(e);
        float r = fmaf(bb.x, wr.x, fmaf(bb.y, wr.y, fmaf(bb.z, wr.z, bb.w * wr.w))) + bi_r;
        const float rs = silu_f(r);

        float s = w0.x * dl[0];
        s = fmaf(w0.y, dl[1],  s); s = fmaf(w0.z, dl[2],  s); s = fmaf(w0.w, dl[3],  s);
        s = fmaf(w1.x, dl[4],  s); s = fmaf(w1.y, dl[5],  s); s = fmaf(w1.z, dl[6],  s);
        s = fmaf(w1.w, dl[7],  s); s = fmaf(w2.x, dl[8],  s); s = fmaf(w2.y, dl[9],  s);
        s = fmaf(w2.z, dl[10], s); s = fmaf(w2.w, dl[11], s); s = fmaf(w3.x, dl[12], s);
        s = fmaf(w3.y, dl[13], s); s = fmaf(w3.z, dl[14], s); s = fmaf(w3.w, dl[15], s);

        const float dt  = softplus_f(s + bdt);
        const float edt = e * dt;
        const float ye  = dd * e;

        if (!a_ready) {                       // uniform branch: A given as A_log
            a0.x = -__expf(a0.x); a0.y = -__expf(a0.y); a0.z = -__expf(a0.z); a0.w = -__expf(a0.w);
            a1.x = -__expf(a1.x); a1.y = -__expf(a1.y); a1.z = -__expf(a1.z); a1.w = -__expf(a1.w);
            a2.x = -__expf(a2.x); a2.y = -__expf(a2.y); a2.z = -__expf(a2.z); a2.w = -__expf(a2.w);
            a3.x = -__expf(a3.x); a3.y = -__expf(a3.y); a3.z = -__expf(a3.z); a3.w = -__expf(a3.w);
        }

        float4 hn0, hn1, hn2, hn3;
        hn0.x = fmaf(h0.x, __expf(dt * a0.x), edt * Bn[0]);
        hn0.y = fmaf(h0.y, __expf(dt * a0.y), edt * Bn[1]);
        hn0.z = fmaf(h0.z, __expf(dt * a0.z), edt * Bn[2]);
        hn0.w = fmaf(h0.w, __expf(dt * a0.w), edt * Bn[3]);
        hn1.x = fmaf(h1.x, __expf(dt * a1.x), edt * Bn[4]);
        hn1.y = fmaf(h1.y, __expf(dt * a1.y), edt * Bn[5]);
        hn1.z = fmaf(h1.z, __expf(dt * a1.z), edt * Bn[6]);
        hn1.w = fmaf(h1.w, __expf(dt * a1.w), edt * Bn[7]);
        hn2.x = fmaf(h2.x, __expf(dt * a2.x), edt * Bn[8]);
        hn2.y = fmaf(h2.y, __expf(dt * a2.y), edt * Bn[9]);
        hn2.z = fmaf(h2.z, __expf(dt * a2.z), edt * Bn[10]);
        hn2.w = fmaf(h2.w, __expf(dt * a2.w), edt * Bn[11]);
        hn3.x = fmaf(h3.x, __expf(dt * a3.x), edt * Bn[12]);
        hn3.y = fmaf(h3.y, __expf(dt * a3.y), edt * Bn[13]);
        hn3.z = fmaf(h3.z, __expf(dt * a3.z), edt * Bn[14]);
        hn3.w = fmaf(h3.w, __expf(dt * a3.w), edt * Bn[15]);

        // write-once stream: nontemporal, keep L3 for h_in
        __builtin_nontemporal_store(*(const f32x4*)&hn0, (f32x4*)(hout4 + q + 0));
        __builtin_nontemporal_store(*(const f32x4*)&hn1, (f32x4*)(hout4 + q + 1));
        __builtin_nontemporal_store(*(const f32x4*)&hn2, (f32x4*)(hout4 + q + 2));
        __builtin_nontemporal_store(*(const f32x4*)&hn3, (f32x4*)(hout4 + q + 3));

        // full n-dot in registers, no cross-lane
        float ys = hn0.x * Cn[0];
        ys = fmaf(hn0.y, Cn[1],  ys); ys = fmaf(hn0.z, Cn[2],  ys); ys = fmaf(hn0.w, Cn[3],  ys);
        ys = fmaf(hn1.x, Cn[4],  ys); ys = fmaf(hn1.y, Cn[5],  ys); ys = fmaf(hn1.z, Cn[6],  ys);
        ys = fmaf(hn1.w, Cn[7],  ys); ys = fmaf(hn2.x, Cn[8],  ys); ys = fmaf(hn2.y, Cn[9],  ys);
        ys = fmaf(hn2.z, Cn[10], ys); ys = fmaf(hn2.w, Cn[11], ys); ys = fmaf(hn3.x, Cn[12], ys);
        ys = fmaf(hn3.y, Cn[13], ys); ys = fmaf(hn3.z, Cn[14], ys); ys = fmaf(hn3.w, Cn[15], ys);

        const float y = (ys + ye) * rs;
        acc0 = fmaf(y, wo0, acc0);
        acc1 = fmaf(y, wo1, acc1);
        acc2 = fmaf(y, wo2, acc2);
        acc3 = fmaf(y, wo3, acc3);
    }

    // ---- out reduction: all 64 lanes hold partials
    #pragma unroll
    for (int off = 1; off < 64; off <<= 1) {
        acc0 += __shfl_xor(acc0, off, 64);
        acc1 += __shfl_xor(acc1, off, 64);
        acc2 += __shfl_xor(acc2, off, 64);
        acc3 += __shfl_xor(acc3, off, 64);
    }
    const int wave = t >> 6;
    if ((t & 63) == 0) {
        red_s[wave][0] = acc0; red_s[wave][1] = acc1;
        red_s[wave][2] = acc2; red_s[wave][3] = acc3;
    }
    __syncthreads();
    if (t == 0) {
        #pragma unroll
        for (int j = 0; j < 4; ++j) {
            out[b * 4 + j] = red_s[0][j] + red_s[1][j] + red_s[2][j] + red_s[3][j]
                           + b_out[j];
        }
    }
}

extern "C" void kernel_launch(void* const* d_in, const int* in_sizes, int n_in,
                              void* d_out, int out_size, void* d_ws, size_t ws_size,
                              hipStream_t stream) {
    const float* bbox   = (const float*)d_in[0];
    const float* h_in   = (const float*)d_in[1];
    const float* fe     = (const float*)d_in[2];
    const float* W_in   = (const float*)d_in[3];
    const float* b_in   = (const float*)d_in[4];
    const float* W_dt   = (const float*)d_in[5];
    const float* b_dt   = (const float*)d_in[6];
    const float* W_flow = (const float*)d_in[7];
    const float* A_log  = (const float*)d_in[8];
    const float* Dvec   = (const float*)d_in[9];
    const float* W_out  = (const float*)d_in[10];
    const float* b_out  = (const float*)d_in[11];

    float* out   = (float*)d_out;
    float* h_out = out + BS * 4;

    const size_t a_bytes = (size_t)DINNER * DSTATE * sizeof(float);  // 128 KB
    const int a_ready = (ws_size >= a_bytes) ? 1 : 0;
    const float* Aptr = A_log;
    if (a_ready) {
        float* Aws = (float*)d_ws;
        hipLaunchKernelGGL(a_precompute_kernel, dim3((DINNER * DSTATE) / 256),
                           dim3(256), 0, stream, A_log, Aws);
        Aptr = Aws;
    }

    hipLaunchKernelGGL(flow_main_kernel, dim3(BS), dim3(256), 0, stream,
                       bbox, h_in, fe, W_in, b_in, W_dt, b_dt, W_flow,
                       Aptr, a_ready, Dvec, W_out, b_out, out, h_out);
}

// Round 2
// 955.142 us; speedup vs baseline: 1.4858x; 1.4858x over previous
//
#include <hip/hip_runtime.h>
#include <math.h>

#define BS      4096
#define DM      256
#define DINNER  2048
#define DSTATE  16
// proj width = DT_RANK + 2*DSTATE = 48
// h row per batch: DINNER*DSTATE = 32768 floats = 8192 float4

__device__ __forceinline__ float silu_f(float x) {
    return x / (1.f + __expf(-x));
}

__device__ __forceinline__ float softplus_f(float x) {
    if (x > 20.f) return x;
    if (x < -20.f) return __expf(x);
    return __logf(1.f + __expf(x));
}

__global__ void a_precompute_kernel(const float* __restrict__ A_log,
                                    float* __restrict__ A) {
    int i = blockIdx.x * 256 + threadIdx.x;   // 32768 total
    A[i] = -__expf(A_log[i]);
}

__global__ __launch_bounds__(256, 4)
void flow_main_kernel(const float* __restrict__ bbox,
                      const float* __restrict__ h_in,
                      const float* __restrict__ flow_embed,
                      const float* __restrict__ W_in,
                      const float* __restrict__ b_in,
                      const float* __restrict__ W_dt,
                      const float* __restrict__ b_dt,
                      const float* __restrict__ W_flow,
                      const float* __restrict__ Aptr,  // -exp(A_log) if a_ready, else A_log
                      int a_ready,
                      const float* __restrict__ Dvec,
                      const float* __restrict__ W_out,
                      const float* __restrict__ b_out,
                      float* __restrict__ out,
                      float* __restrict__ h_out)
{
    __shared__ __align__(16) float fe_s[DM];
    __shared__ float proj_s[48];
    __shared__ float pp_s[48][4];
    __shared__ float dt_s[DINNER];
    __shared__ float edt_s[DINNER];
    __shared__ float ye_s[DINNER];
    __shared__ float rs_s[DINNER];
    __shared__ float red_s[4][4];

    const int b = blockIdx.x;
    const int t = threadIdx.x;

    // ---- phase 0: flow_embed row to LDS, proj_f = fe @ W_flow.T (48 outputs)
    fe_s[t] = flow_embed[b * DM + t];
    __syncthreads();

    if (t < 192) {
        const int k = t >> 2, p = t & 3;
        const float4* wf  = (const float4*)(W_flow + k * DM);
        const float4* fe4 = (const float4*)fe_s;
        float s = 0.f;
        #pragma unroll
        for (int i = 0; i < 16; ++i) {
            float4 w = wf[p * 16 + i];
            float4 f = fe4[p * 16 + i];
            s += w.x * f.x + w.y * f.y + w.z * f.z + w.w * f.w;
        }
        pp_s[k][p] = s;
    }
    __syncthreads();
    if (t < 48)
        proj_s[t] = pp_s[t][0] + pp_s[t][1] + pp_s[t][2] + pp_s[t][3];
    __syncthreads();

    // ---- phase 1: per-d scalars: dt (softplus), e=silu, cache dt, e*dt, D*e, silu(r)
    float dl[16];
    #pragma unroll
    for (int k = 0; k < 16; ++k) dl[k] = proj_s[k];
    const float4 bb = ((const float4*)bbox)[b];

    #pragma unroll
    for (int i = 0; i < 8; ++i) {
        const int d = t + i * 256;
        float4 wi = ((const float4*)W_in)[d];
        float e = fmaf(bb.x, wi.x, fmaf(bb.y, wi.y, fmaf(bb.z, wi.z, bb.w * wi.w))) + b_in[d];
        e = silu_f(e);
        float4 wr = ((const float4*)W_in)[DINNER + d];
        float r = fmaf(bb.x, wr.x, fmaf(bb.y, wr.y, fmaf(bb.z, wr.z, bb.w * wr.w))) + b_in[DINNER + d];
        const float rs = silu_f(r);

        const float4* wd = (const float4*)(W_dt + d * 16);
        float s = 0.f;
        #pragma unroll
        for (int j = 0; j < 4; ++j) {
            float4 w = wd[j];
            s += w.x * dl[j * 4 + 0] + w.y * dl[j * 4 + 1] +
                 w.z * dl[j * 4 + 2] + w.w * dl[j * 4 + 3];
        }
        const float dt = softplus_f(s + b_dt[d]);

        dt_s[d]  = dt;
        edt_s[d] = e * dt;
        ye_s[d]  = Dvec[d] * e;
        rs_s[d]  = rs;
    }
    __syncthreads();

    // ---- main loop: stream the 128 KB h row as float4; thread owns (d, n-quad).
    // Explicit 4-deep rotating software pipeline: loads for iterations
    // it..it+3 are always in flight (structural MLP, not compiler-dependent).
    const int nq = t & 3;
    float Bq[4], Cq[4];
    #pragma unroll
    for (int j = 0; j < 4; ++j) {
        Bq[j] = proj_s[16 + nq * 4 + j];
        Cq[j] = proj_s[32 + nq * 4 + j];
    }

    const float4* __restrict__ hin4  = (const float4*)(h_in + (size_t)b * 32768);
    float4* __restrict__       hout4 = (float4*)(h_out + (size_t)b * 32768);
    const float4* __restrict__ A4    = (const float4*)Aptr;

    float acc0 = 0.f, acc1 = 0.f, acc2 = 0.f, acc3 = 0.f;

    float4 hp[4], ap[4];
    #pragma unroll
    for (int k = 0; k < 4; ++k) {
        hp[k] = hin4[k * 256 + t];
        ap[k] = A4[k * 256 + t];
    }

    auto body = [&](int it, float4 h, float4 a) {
        const int idx = it * 256 + t;     // float4 index in row; flat = idx*4
        const int d   = idx >> 2;
        if (!a_ready) {                   // uniform branch: A given as A_log
            a.x = -__expf(a.x); a.y = -__expf(a.y);
            a.z = -__expf(a.z); a.w = -__expf(a.w);
        }
        const float dt  = dt_s[d];
        const float edt = edt_s[d];
        float4 hn;
        hn.x = fmaf(h.x, __expf(dt * a.x), edt * Bq[0]);
        hn.y = fmaf(h.y, __expf(dt * a.y), edt * Bq[1]);
        hn.z = fmaf(h.z, __expf(dt * a.z), edt * Bq[2]);
        hn.w = fmaf(h.w, __expf(dt * a.w), edt * Bq[3]);
        hout4[idx] = hn;

        float ys = hn.x * Cq[0] + hn.y * Cq[1] + hn.z * Cq[2] + hn.w * Cq[3];
        ys += __shfl_xor(ys, 1, 64);
        ys += __shfl_xor(ys, 2, 64);      // all 4 lanes of the d-group hold full sum
        if (nq == 0) {
            const float y = (ys + ye_s[d]) * rs_s[d];
            acc0 = fmaf(y, W_out[d],          acc0);
            acc1 = fmaf(y, W_out[DINNER + d], acc1);
            acc2 = fmaf(y, W_out[2 * DINNER + d], acc2);
            acc3 = fmaf(y, W_out[3 * DINNER + d], acc3);
        }
    };

    // steady state: consume stage (it&3), immediately refill with it+4
    #pragma unroll 4
    for (int it = 0; it < 28; ++it) {
        const int k = it & 3;             // static under unroll-4
        float4 h = hp[k], a = ap[k];
        hp[k] = hin4[(it + 4) * 256 + t];
        ap[k] = A4[(it + 4) * 256 + t];
        body(it, h, a);
    }
    // epilogue: drain remaining 4 stages
    #pragma unroll 4
    for (int it = 28; it < 32; ++it) {
        const int k = it & 3;
        body(it, hp[k], ap[k]);
    }

    // ---- out reduction: only nq==0 lanes hold nonzero partials
    #pragma unroll
    for (int off = 4; off < 64; off <<= 1) {
        acc0 += __shfl_xor(acc0, off, 64);
        acc1 += __shfl_xor(acc1, off, 64);
        acc2 += __shfl_xor(acc2, off, 64);
        acc3 += __shfl_xor(acc3, off, 64);
    }
    const int wave = t >> 6;
    if ((t & 63) == 0) {
        red_s[wave][0] = acc0; red_s[wave][1] = acc1;
        red_s[wave][2] = acc2; red_s[wave][3] = acc3;
    }
    __syncthreads();
    if (t == 0) {
        #pragma unroll
        for (int j = 0; j < 4; ++j) {
            out[b * 4 + j] = red_s[0][j] + red_s[1][j] + red_s[2][j] + red_s[3][j]
                           + b_out[j];
        }
    }
}

extern "C" void kernel_launch(void* const* d_in, const int* in_sizes, int n_in,
                              void* d_out, int out_size, void* d_ws, size_t ws_size,
                              hipStream_t stream) {
    const float* bbox   = (const float*)d_in[0];
    const float* h_in   = (const float*)d_in[1];
    const float* fe     = (const float*)d_in[2];
    const float* W_in   = (const float*)d_in[3];
    const float* b_in   = (const float*)d_in[4];
    const float* W_dt   = (const float*)d_in[5];
    const float* b_dt   = (const float*)d_in[6];
    const float* W_flow = (const float*)d_in[7];
    const float* A_log  = (const float*)d_in[8];
    const float* Dvec   = (const float*)d_in[9];
    const float* W_out  = (const float*)d_in[10];
    const float* b_out  = (const float*)d_in[11];

    float* out   = (float*)d_out;
    float* h_out = out + BS * 4;

    const size_t a_bytes = (size_t)DINNER * DSTATE * sizeof(float);  // 128 KB
    const int a_ready = (ws_size >= a_bytes) ? 1 : 0;
    const float* Aptr = A_log;
    if (a_ready) {
        float* Aws = (float*)d_ws;
        hipLaunchKernelGGL(a_precompute_kernel, dim3((DINNER * DSTATE) / 256),
                           dim3(256), 0, stream, A_log, Aws);
        Aptr = Aws;
    }

    hipLaunchKernelGGL(flow_main_kernel, dim3(BS), dim3(256), 0, stream,
                       bbox, h_in, fe, W_in, b_in, W_dt, b_dt, W_flow,
                       Aptr, a_ready, Dvec, W_out, b_out, out, h_out);
}